// Round 15
// baseline (358.950 us; speedup 1.0000x reference)
//
#include <hip/hip_runtime.h>

typedef unsigned short ushort_t;
typedef __attribute__((ext_vector_type(8))) short short8;   // 8 bf16 (4 VGPRs)
typedef __attribute__((ext_vector_type(4))) float f32x4;

#define S_  2048
#define Dm  2048
#define NH  16
#define NKV 4
#define HD_ 128
// SCALE * log2(e): exp(s*SCALE) == exp2(s*C2)
#define C2_ 0.12751879524465536f

__device__ __forceinline__ ushort_t f2bf(float f) {
  union { float f; unsigned u; } v; v.f = f;
  unsigned u = v.u;
  return (ushort_t)((u + 0x7FFFu + ((u >> 16) & 1u)) >> 16);   // RNE
}
__device__ __forceinline__ ushort_t f2bf2(float f) {            // round-half-up (2 VALU ops)
  union { float f; unsigned u; } v; v.f = f;
  return (ushort_t)((v.u + 0x8000u) >> 16);
}
__device__ __forceinline__ float bf2f(ushort_t h) {
  union { unsigned u; float f; } v; v.u = ((unsigned)h) << 16;
  return v.f;
}
__device__ __forceinline__ void gl_lds16(const void* g, void* l) {
  __builtin_amdgcn_global_load_lds((const __attribute__((address_space(1))) void*)g,
                                   (__attribute__((address_space(3))) void*)l, 16, 0, 0);
}

// ---------------- merged prep: bf16 convert (blocks <8192) + 4 weight transposes ----------------
__global__ void prep_k(const float* __restrict__ hs, ushort_t* __restrict__ hsb,
                       const float* __restrict__ Wq, const float* __restrict__ Wk,
                       const float* __restrict__ Wv, const float* __restrict__ Wo,
                       ushort_t* __restrict__ wtqkv, ushort_t* __restrict__ wto) {
  __shared__ float tile[32][33];
  const int id = blockIdx.x;
  if (id < 8192) {
    int i = id * 256 + threadIdx.x;
    float4 v = ((const float4*)hs)[i];
    union { ushort_t u[4]; uint2 v2; } o;
    o.u[0] = f2bf(v.x); o.u[1] = f2bf(v.y); o.u[2] = f2bf(v.z); o.u[3] = f2bf(v.w);
    *(uint2*)&hsb[(size_t)i * 4] = o.v2;
    return;
  }
  const int id2 = id - 8192;
  const int z = id2 >> 12, ky = (id2 >> 6) & 63, nx = id2 & 63;
  const float* src;
  ushort_t* dst;
  int N;
  switch (z) {
    case 0: src = Wq; dst = wtqkv; N = 2048; break;
    case 1: src = Wk; dst = wtqkv + (size_t)2048 * 2048; N = 512; break;
    case 2: src = Wv; dst = wtqkv + (size_t)2560 * 2048; N = 512; break;
    default: src = Wo; dst = wto; N = 2048; break;
  }
  int n0 = nx * 32, k0 = ky * 32;
  if (n0 >= N) return;
  int c = threadIdx.x & 31, r = threadIdx.x >> 5;   // r: 0..7
#pragma unroll
  for (int i = 0; i < 32; i += 8)
    tile[r + i][c] = src[(size_t)(k0 + r + i) * N + n0 + c];
  __syncthreads();
#pragma unroll
  for (int i = 0; i < 32; i += 8)
    dst[(size_t)(n0 + r + i) * 2048 + k0 + c] = f2bf(tile[c][r + i]);
}

// ---------------- GEMM QKV (dbuf, XCD swizzle) + bias + fused RoPE + fused V-transpose ----------
__global__ __launch_bounds__(256, 2) void gemm_qkv_k(
    const ushort_t* __restrict__ A, const ushort_t* __restrict__ Bt, ushort_t* __restrict__ C,
    const float* __restrict__ bq, const float* __restrict__ bk2, const float* __restrict__ bv,
    const float* __restrict__ cosT, const float* __restrict__ sinT, ushort_t* __restrict__ vt) {
  const int N = 3072, K = 2048;
  __shared__ ushort_t smem[16384];   // 32 KB: staging dbuf; later transpose tile / rope fbuf
  ushort_t* lA0 = smem;              // [2][4096], source-pre-swizzled: slot ^= (row>>1)&3
  ushort_t* lB0 = smem + 8192;
  const int lin = blockIdx.x;                    // 768 blocks
  const int nid = (lin & 7) * 96 + (lin >> 3);   // XCD-chunked swizzle (768%8==0)
  const int n0 = (nid % 24) * 128, m0 = (nid / 24) * 128;
  const int t = threadIdx.x;
  const int w = t >> 6, l = t & 63, lr = l & 15, lg = l >> 4;
  const int wr = w >> 1, wc = w & 1;
  const int srow = t >> 2, ssl = t & 3;

  auto stage = [&](int kt, int bufi) {
    int r0 = srow, r1 = srow + 64;
    gl_lds16(A + (size_t)(m0 + r0) * K + kt + ((ssl ^ ((r0 >> 1) & 3)) << 3),
             &lA0[bufi * 4096 + w * 512]);
    gl_lds16(A + (size_t)(m0 + r1) * K + kt + ((ssl ^ ((r1 >> 1) & 3)) << 3),
             &lA0[bufi * 4096 + 2048 + w * 512]);
    gl_lds16(Bt + (size_t)(n0 + r0) * K + kt + ((ssl ^ ((r0 >> 1) & 3)) << 3),
             &lB0[bufi * 4096 + w * 512]);
    gl_lds16(Bt + (size_t)(n0 + r1) * K + kt + ((ssl ^ ((r1 >> 1) & 3)) << 3),
             &lB0[bufi * 4096 + 2048 + w * 512]);
  };

  f32x4 acc[4][4];
#pragma unroll
  for (int i = 0; i < 4; i++)
#pragma unroll
    for (int j = 0; j < 4; j++) acc[i][j] = (f32x4){0.f, 0.f, 0.f, 0.f};

  stage(0, 0);
  const int nit = K / 32;   // 64
  for (int it = 0; it < nit; it++) {
    const int cur = it & 1;
    if (it + 1 < nit) {
      stage((it + 1) * 32, cur ^ 1);
      asm volatile("s_waitcnt vmcnt(4)" ::: "memory");   // current tile's 4 loads done
    } else {
      asm volatile("s_waitcnt vmcnt(0)" ::: "memory");
    }
    __builtin_amdgcn_s_barrier();
    short8 af[4], bfr[4];
#pragma unroll
    for (int mi = 0; mi < 4; mi++) {
      int row = wr * 64 + mi * 16 + lr;
      af[mi] = *(const short8*)((const char*)(lA0 + cur * 4096) + row * 64 +
                                ((lg ^ ((row >> 1) & 3)) << 4));
    }
#pragma unroll
    for (int ni = 0; ni < 4; ni++) {
      int row = wc * 64 + ni * 16 + lr;
      bfr[ni] = *(const short8*)((const char*)(lB0 + cur * 4096) + row * 64 +
                                 ((lg ^ ((row >> 1) & 3)) << 4));
    }
#pragma unroll
    for (int mi = 0; mi < 4; mi++)
#pragma unroll
      for (int ni = 0; ni < 4; ni++)
        acc[mi][ni] = __builtin_amdgcn_mfma_f32_16x16x32_bf16(af[mi], bfr[ni], acc[mi][ni], 0, 0, 0);
    __builtin_amdgcn_s_barrier();   // all waves done reading buf[cur] before restage
  }

  // epilogue: bias; RoPE (Q/K blocks) via partner-wave LDS exchange; V blocks also fill
  // the LDS transpose tile for the fused vt write.
  const bool isV = (n0 >= 2560);
  float* fbuf = (float*)smem;        // 16 KB, staging done
  const int pw_ = w ^ 1;             // partner wave: same wr, wc^1
#pragma unroll
  for (int mi = 0; mi < 4; mi++) {
    float vv[4][4];
#pragma unroll
    for (int ni = 0; ni < 4; ni++)
#pragma unroll
      for (int r = 0; r < 4; r++) {
        int col = n0 + wc * 64 + ni * 16 + lr;
        float bias = (col < 2048) ? bq[col] : (col < 2560) ? bk2[col - 2048] : bv[col - 2560];
        vv[ni][r] = acc[mi][ni][r] + bias;
      }
    if (!isV) {
      __syncthreads();
#pragma unroll
      for (int ni = 0; ni < 4; ni++)
#pragma unroll
        for (int r = 0; r < 4; r++)
          fbuf[w * 1024 + (lg * 4 + r) * 64 + ni * 16 + lr] = vv[ni][r];
      __syncthreads();
#pragma unroll
      for (int ni = 0; ni < 4; ni++)
#pragma unroll
        for (int r = 0; r < 4; r++) {
          float pv = fbuf[pw_ * 1024 + (lg * 4 + r) * 64 + ni * 16 + lr];
          int row = m0 + wr * 64 + mi * 16 + lg * 4 + r;   // = b*2048+s
          int d = wc * 64 + ni * 16 + lr;                  // 0..127 within head
          float c = cosT[(size_t)row * HD_ + d];
          float sn = sinT[(size_t)row * HD_ + d];
          vv[ni][r] = (wc == 0) ? vv[ni][r] * c - pv * sn : vv[ni][r] * c + pv * sn;
        }
    }
#pragma unroll
    for (int ni = 0; ni < 4; ni++)
#pragma unroll
      for (int r = 0; r < 4; r++) {
        int row = m0 + wr * 64 + mi * 16 + lg * 4 + r;
        int col = n0 + wc * 64 + ni * 16 + lr;
        ushort_t hv = f2bf(vv[ni][r]);
        C[(size_t)row * N + col] = hv;
        if (isV) {
          int colL = wc * 64 + ni * 16 + lr;            // d within head
          int rowL = wr * 64 + mi * 16 + lg * 4 + r;    // s within tile
          smem[colL * 128 + (rowL ^ ((colL & 7) << 4))] = hv;
        }
      }
  }
  if (isV) {
    __syncthreads();
    const int kvh = (n0 - 2560) >> 7;
    const int b = m0 >> 11, s0v = m0 & 2047;
    const size_t vbase = (size_t)(b * 4 + kvh) * 128;
#pragma unroll
    for (int j = 0; j < 8; j++) {
      int cid = j * 256 + t;
      int d = cid >> 4, sc = cid & 15;
      int rowStart = (sc * 8) ^ ((d & 7) << 4);
      short8 v8 = *(const short8*)&smem[d * 128 + rowStart];
      *(short8*)&vt[(vbase + d) * S_ + s0v + sc * 8] = v8;
    }
  }
}

// ---------------- fused causal GQA attention + attn_weights, single pass + norm sweep ---------
// 512 blocks (XCD-chunk swizzled; each XCD chunk shares one (b,kvh) K/V panel -> L2-hot).
// Block handles q-tiles {pi, 31-pi}: constant 33 k-tiles. Per q-tile:
//  sweep 1: QK^T (K dbuf in LDS) + exp2 + PV with V read DIRECT from L2 (no LDS staging)
//  epilogue: normalized attnO (bf16) + zero-fill of outW upper triangle
//  sweep 2: QK^T recompute (dbuf K only, L2-hot) -> outW = exp2 * inv_l (fp32, causal region)
__global__ __launch_bounds__(256, 2) void attn_k(
    const ushort_t* __restrict__ qkv, const ushort_t* __restrict__ vt,
    ushort_t* __restrict__ attnO, float* __restrict__ outW) {
  __shared__ ushort_t lK[2][64 * 128];   // [k][d], 16 slots/row, slot ^= row&15  (32 KB)
  __shared__ ushort_t lP[4][16 * 64];    // per-wave P~ (16 rows), slot ^= row&7  (8 KB)
  const int nid = (blockIdx.x & 7) * 64 + (blockIdx.x >> 3);   // 512%8==0, bijective
  const int pairI = nid & 15, h = (nid >> 4) & 15, b = nid >> 8;
  const int kvh = h >> 2;
  const int t = threadIdx.x, w = t >> 6, l = t & 63, lr = l & 15, lg = l >> 4;
  ushort_t* lPw = lP[w];
  const ushort_t* vpanel = vt + (size_t)((b * 4 + kvh) * 128) * S_;   // [128][2048], L2-hot

  auto stageK = [&](int kt, int bufi) {
#pragma unroll
    for (int c = 0; c < 4; c++) {
      int row = c * 16 + (t >> 4), sl = t & 15;
      gl_lds16(qkv + (size_t)(b * S_ + kt * 64 + row) * 3072 + 2048 + kvh * HD_ +
                   ((sl ^ (row & 15)) << 3),
               &lK[bufi][c * 2048 + w * 512]);
    }
  };

  for (int sel = 0; sel < 2; sel++) {
    const int qt = sel ? (31 - pairI) : pairI;   // 64-row q-tile index, 0..31
    const int qw = qt * 64 + w * 16;             // this wave's 16 q-rows
    const int nkt = qt + 1;                      // 64-wide k-tiles in causal range

    // Q fragments (A-frag: row=lane&15, k=(lane>>4)*8+i)
    short8 qf[4];
#pragma unroll
    for (int kc = 0; kc < 4; kc++)
      qf[kc] = *(const short8*)&qkv[(size_t)(b * S_ + qw + lr) * 3072 + h * HD_ + kc * 32 + lg * 8];

    float lsum[4];
    f32x4 o[8];
#pragma unroll
    for (int r = 0; r < 4; r++) lsum[r] = 0.f;
#pragma unroll
    for (int dj = 0; dj < 8; dj++) o[dj] = (f32x4){0.f, 0.f, 0.f, 0.f};

    // ======== sweep 1: attention accumulate (K staged dbuf; V direct from L2) ========
    stageK(0, 0);
    for (int kt = 0; kt < nkt; kt++) {
      const int cur = kt & 1;
      if (kt + 1 < nkt) {
        stageK(kt + 1, cur ^ 1);
        asm volatile("s_waitcnt vmcnt(4)" ::: "memory");   // current tile's 4 K loads done
      } else {
        asm volatile("s_waitcnt vmcnt(0)" ::: "memory");
      }
      __builtin_amdgcn_s_barrier();

      // S = Q K^T
      f32x4 s[4];
#pragma unroll
      for (int ni = 0; ni < 4; ni++) s[ni] = (f32x4){0.f, 0.f, 0.f, 0.f};
      __builtin_amdgcn_s_setprio(1);
#pragma unroll
      for (int kc = 0; kc < 4; kc++) {
        short8 kf[4];
#pragma unroll
        for (int ni = 0; ni < 4; ni++) {
          int row = ni * 16 + lr;
          kf[ni] = *(const short8*)((const char*)lK[cur] + row * 256 +
                                    (((kc * 4 + lg) ^ (row & 15)) << 4));
        }
#pragma unroll
        for (int ni = 0; ni < 4; ni++)
          s[ni] = __builtin_amdgcn_mfma_f32_16x16x32_bf16(qf[kc], kf[ni], s[ni], 0, 0, 0);
      }
      __builtin_amdgcn_s_setprio(0);

      // P~ = exp2(S*C2); mask only on the diagonal tile (separate clean path otherwise)
      if (kt == nkt - 1) {
#pragma unroll
        for (int ni = 0; ni < 4; ni++)
#pragma unroll
          for (int r = 0; r < 4; r++) {
            float p = exp2f(s[ni][r] * C2_);
            int colg = kt * 64 + ni * 16 + lr;
            int rowg = qw + lg * 4 + r;
            if (colg > rowg) p = 0.f;
            lsum[r] += p;
            int rowl = lg * 4 + r, col = ni * 16 + lr;
            lPw[rowl * 64 + (((col >> 3) ^ (rowl & 7)) << 3) + (col & 7)] = f2bf2(p);
          }
      } else {
#pragma unroll
        for (int ni = 0; ni < 4; ni++)
#pragma unroll
          for (int r = 0; r < 4; r++) {
            float p = exp2f(s[ni][r] * C2_);
            lsum[r] += p;
            int rowl = lg * 4 + r, col = ni * 16 + lr;
            lPw[rowl * 64 + (((col >> 3) ^ (rowl & 7)) << 3) + (col & 7)] = f2bf2(p);
          }
      }

      // O += P~ V   (V fragments direct from global; panel is L2-resident on this XCD)
      __builtin_amdgcn_s_setprio(1);
#pragma unroll
      for (int kc = 0; kc < 2; kc++) {
        short8 pa;
        {
          int row = lr;
          pa = *(const short8*)((const char*)lPw + row * 128 + (((kc * 4 + lg) ^ (row & 7)) << 4));
        }
        const ushort_t* vcol = vpanel + (size_t)kt * 64 + (kc * 4 + lg) * 8;
#pragma unroll
        for (int dj = 0; dj < 8; dj++) {
          short8 vb = *(const short8*)&vcol[(size_t)(dj * 16 + lr) * S_];
          o[dj] = __builtin_amdgcn_mfma_f32_16x16x32_bf16(pa, vb, o[dj], 0, 0, 0);
        }
      }
      __builtin_amdgcn_s_setprio(0);
      __builtin_amdgcn_s_barrier();   // all waves done reading lK[cur] before restage
    }

    // row-sum reduce over the 16 lr lanes -> inv_l (registers only)
    float inv_l[4];
#pragma unroll
    for (int r = 0; r < 4; r++) {
      float sum = lsum[r];
#pragma unroll
      for (int off = 1; off < 16; off <<= 1) sum += __shfl_xor(sum, off);
      inv_l[r] = 1.f / sum;
    }
    // normalized O -> attn buffer (bf16)
#pragma unroll
    for (int dj = 0; dj < 8; dj++)
#pragma unroll
      for (int r = 0; r < 4; r++) {
        int rowg = b * S_ + qw + lg * 4 + r;
        int colg = h * HD_ + dj * 16 + lr;
        attnO[(size_t)rowg * Dm + colg] = f2bf(o[dj][r] * inv_l[r]);
      }

    // zero-fill outW strict upper triangle for this wave's 16 rows (cols >= nkt*64).
    {
      const int zc0 = nkt * 64;
      const int zn = (S_ - zc0) >> 2;   // float4 per row (multiple of 16, may be 0)
      f32x4 z = {0.f, 0.f, 0.f, 0.f};
      const int bh = b * NH + h;
      for (int rr = 0; rr < 16; rr++) {
        f32x4* base = (f32x4*)&outW[((size_t)bh * S_ + qw + rr) * S_ + zc0];
        for (int cc = l; cc < zn; cc += 64) __builtin_nontemporal_store(z, base + cc);
      }
    }

    // ======== sweep 2: recompute QK^T (K only, L2-hot), write normalized fp32 outW ========
    {
      const int bh = b * NH + h;
      stageK(0, 0);
      for (int kt = 0; kt < nkt; kt++) {
        const int cur = kt & 1;
        if (kt + 1 < nkt) {
          stageK(kt + 1, cur ^ 1);
          asm volatile("s_waitcnt vmcnt(4)" ::: "memory");
        } else {
          asm volatile("s_waitcnt vmcnt(0)" ::: "memory");
        }
        __builtin_amdgcn_s_barrier();

        f32x4 s[4];
#pragma unroll
        for (int ni = 0; ni < 4; ni++) s[ni] = (f32x4){0.f, 0.f, 0.f, 0.f};
        __builtin_amdgcn_s_setprio(1);
#pragma unroll
        for (int kc = 0; kc < 4; kc++) {
          short8 kf[4];
#pragma unroll
          for (int ni = 0; ni < 4; ni++) {
            int row = ni * 16 + lr;
            kf[ni] = *(const short8*)((const char*)lK[cur] + row * 256 +
                                      (((kc * 4 + lg) ^ (row & 15)) << 4));
          }
#pragma unroll
          for (int ni = 0; ni < 4; ni++)
            s[ni] = __builtin_amdgcn_mfma_f32_16x16x32_bf16(qf[kc], kf[ni], s[ni], 0, 0, 0);
        }
        __builtin_amdgcn_s_setprio(0);

        const bool diag = (kt == nkt - 1);
#pragma unroll
        for (int ni = 0; ni < 4; ni++)
#pragma unroll
          for (int r = 0; r < 4; r++) {
            int colg = kt * 64 + ni * 16 + lr;
            int rowg = qw + lg * 4 + r;
            float p = exp2f(s[ni][r] * C2_) * inv_l[r];
            if (diag && colg > rowg) p = 0.f;
            outW[((size_t)bh * S_ + rowg) * S_ + colg] = p;
          }
        __builtin_amdgcn_s_barrier();   // all waves done reading lK[cur] before restage
      }
    }
  }
}

// ---------------- tail: pure Wo projection GEMM (dbuf, XCD swizzle), full machine -------------
__global__ __launch_bounds__(256, 2) void tail_k(
    const ushort_t* __restrict__ A, const ushort_t* __restrict__ Bt, float* __restrict__ outO) {
  __shared__ ushort_t sh[2][64 * 128];   // 32 KB
  const int t = threadIdx.x;
  const int w = t >> 6, l = t & 63, lr = l & 15, lg = l >> 4;
  const int N = 2048, K = 2048;
  const int nid = (blockIdx.x & 7) * 64 + (blockIdx.x >> 3);   // XCD-chunked, 512%8==0
  const int n0 = (nid & 15) * 128, m0 = (nid >> 4) * 128;
  const int wr = w >> 1, wc = w & 1;
  const int srow = t >> 2, ssl = t & 3;

  auto stageG = [&](int kt, int bufi) {
    int r0 = srow, r1 = srow + 64;
    gl_lds16(A + (size_t)(m0 + r0) * K + kt + ((ssl ^ ((r0 >> 1) & 3)) << 3), &sh[bufi][w * 512]);
    gl_lds16(A + (size_t)(m0 + r1) * K + kt + ((ssl ^ ((r1 >> 1) & 3)) << 3),
             &sh[bufi][2048 + w * 512]);
    gl_lds16(Bt + (size_t)(n0 + r0) * K + kt + ((ssl ^ ((r0 >> 1) & 3)) << 3),
             &sh[bufi][4096 + w * 512]);
    gl_lds16(Bt + (size_t)(n0 + r1) * K + kt + ((ssl ^ ((r1 >> 1) & 3)) << 3),
             &sh[bufi][4096 + 2048 + w * 512]);
  };

  f32x4 acc[4][4];
#pragma unroll
  for (int i = 0; i < 4; i++)
#pragma unroll
    for (int j = 0; j < 4; j++) acc[i][j] = (f32x4){0.f, 0.f, 0.f, 0.f};

  stageG(0, 0);
  const int nit = K / 32;
  for (int it = 0; it < nit; it++) {
    const int cur = it & 1;
    if (it + 1 < nit) {
      stageG((it + 1) * 32, cur ^ 1);
      asm volatile("s_waitcnt vmcnt(4)" ::: "memory");
    } else {
      asm volatile("s_waitcnt vmcnt(0)" ::: "memory");
    }
    __builtin_amdgcn_s_barrier();
    short8 af[4], bfr[4];
#pragma unroll
    for (int mi = 0; mi < 4; mi++) {
      int row = wr * 64 + mi * 16 + lr;
      af[mi] =
          *(const short8*)((const char*)&sh[cur][0] + row * 64 + ((lg ^ ((row >> 1) & 3)) << 4));
    }
#pragma unroll
    for (int ni = 0; ni < 4; ni++) {
      int row = wc * 64 + ni * 16 + lr;
      bfr[ni] = *(const short8*)((const char*)&sh[cur][4096] + row * 64 +
                                 ((lg ^ ((row >> 1) & 3)) << 4));
    }
#pragma unroll
    for (int mi = 0; mi < 4; mi++)
#pragma unroll
      for (int ni = 0; ni < 4; ni++)
        acc[mi][ni] =
            __builtin_amdgcn_mfma_f32_16x16x32_bf16(af[mi], bfr[ni], acc[mi][ni], 0, 0, 0);
    __builtin_amdgcn_s_barrier();
  }
#pragma unroll
  for (int mi = 0; mi < 4; mi++)
#pragma unroll
    for (int ni = 0; ni < 4; ni++)
#pragma unroll
      for (int r = 0; r < 4; r++) {
        int row = m0 + wr * 64 + mi * 16 + lg * 4 + r;
        int col = n0 + wc * 64 + ni * 16 + lr;
        outO[(size_t)row * N + col] = acc[mi][ni][r];
      }
}

// ---------------- host ----------------
extern "C" void kernel_launch(void* const* d_in, const int* in_sizes, int n_in,
                              void* d_out, int out_size, void* d_ws, size_t ws_size,
                              hipStream_t stream) {
  const float* hs   = (const float*)d_in[0];
  const float* cosT = (const float*)d_in[1];
  const float* sinT = (const float*)d_in[2];
  // d_in[3] attention_mask: pure causal, applied analytically
  const float* Wq = (const float*)d_in[4];
  const float* bq = (const float*)d_in[5];
  const float* Wk = (const float*)d_in[6];
  const float* bk = (const float*)d_in[7];
  const float* Wv = (const float*)d_in[8];
  const float* bv = (const float*)d_in[9];
  const float* Wo = (const float*)d_in[10];

  char* ws = (char*)d_ws;
  ushort_t* hsb   = (ushort_t*)(ws);               // 16,777,216 B  [4096][2048] bf16
  ushort_t* wtqkv = (ushort_t*)(ws + 16777216);    // 12,582,912 B  [3072][2048] bf16 (Wq|Wk|Wv)^T
  ushort_t* wto   = (ushort_t*)(ws + 29360128);    //  8,388,608 B  [2048][2048] bf16 Wo^T
  ushort_t* qkv   = (ushort_t*)(ws + 37748736);    // 25,165,824 B  [4096][3072] bf16
  ushort_t* vt    = (ushort_t*)(ws + 62914560);    //  4,194,304 B  [8][128][2048] bf16
  ushort_t* attn  = (ushort_t*)(ws);               // reuse hsb region (dead after gemm_qkv)

  float* outO = (float*)d_out;            // [2,2048,2048] attn_out
  float* outW = outO + (size_t)8388608;   // [2,16,2048,2048] attn_weights

  prep_k<<<8192 + 16384, 256, 0, stream>>>(hs, hsb, Wq, Wk, Wv, Wo, wtqkv, wto);
  gemm_qkv_k<<<768, 256, 0, stream>>>(hsb, wtqkv, qkv, bq, bk, bv, cosT, sinT, vt);
  attn_k<<<512, 256, 0, stream>>>(qkv, vt, attn, outW);
  tail_k<<<512, 256, 0, stream>>>(attn, wto, outO);
}

// Round 16
// 296.668 us; speedup vs baseline: 1.2099x; 1.2099x over previous
//
#include <hip/hip_runtime.h>

typedef unsigned short ushort_t;
typedef __attribute__((ext_vector_type(8))) short short8;   // 8 bf16 (4 VGPRs)
typedef __attribute__((ext_vector_type(4))) float f32x4;

#define S_  2048
#define Dm  2048
#define NH  16
#define NKV 4
#define HD_ 128
// SCALE * log2(e): exp(s*SCALE) == exp2(s*C2)
#define C2_ 0.12751879524465536f

__device__ __forceinline__ ushort_t f2bf(float f) {
  union { float f; unsigned u; } v; v.f = f;
  unsigned u = v.u;
  return (ushort_t)((u + 0x7FFFu + ((u >> 16) & 1u)) >> 16);   // RNE
}
__device__ __forceinline__ ushort_t f2bf2(float f) {            // round-half-up (2 VALU ops)
  union { float f; unsigned u; } v; v.f = f;
  return (ushort_t)((v.u + 0x8000u) >> 16);
}
__device__ __forceinline__ float bf2f(ushort_t h) {
  union { unsigned u; float f; } v; v.u = ((unsigned)h) << 16;
  return v.f;
}
__device__ __forceinline__ void gl_lds16(const void* g, void* l) {
  __builtin_amdgcn_global_load_lds((const __attribute__((address_space(1))) void*)g,
                                   (__attribute__((address_space(3))) void*)l, 16, 0, 0);
}

// ---------------- merged prep: bf16 convert (blocks <8192) + 4 weight transposes ----------------
__global__ void prep_k(const float* __restrict__ hs, ushort_t* __restrict__ hsb,
                       const float* __restrict__ Wq, const float* __restrict__ Wk,
                       const float* __restrict__ Wv, const float* __restrict__ Wo,
                       ushort_t* __restrict__ wtqkv, ushort_t* __restrict__ wto) {
  __shared__ float tile[32][33];
  const int id = blockIdx.x;
  if (id < 8192) {
    int i = id * 256 + threadIdx.x;
    float4 v = ((const float4*)hs)[i];
    union { ushort_t u[4]; uint2 v2; } o;
    o.u[0] = f2bf(v.x); o.u[1] = f2bf(v.y); o.u[2] = f2bf(v.z); o.u[3] = f2bf(v.w);
    *(uint2*)&hsb[(size_t)i * 4] = o.v2;
    return;
  }
  const int id2 = id - 8192;
  const int z = id2 >> 12, ky = (id2 >> 6) & 63, nx = id2 & 63;
  const float* src;
  ushort_t* dst;
  int N;
  switch (z) {
    case 0: src = Wq; dst = wtqkv; N = 2048; break;
    case 1: src = Wk; dst = wtqkv + (size_t)2048 * 2048; N = 512; break;
    case 2: src = Wv; dst = wtqkv + (size_t)2560 * 2048; N = 512; break;
    default: src = Wo; dst = wto; N = 2048; break;
  }
  int n0 = nx * 32, k0 = ky * 32;
  if (n0 >= N) return;
  int c = threadIdx.x & 31, r = threadIdx.x >> 5;   // r: 0..7
#pragma unroll
  for (int i = 0; i < 32; i += 8)
    tile[r + i][c] = src[(size_t)(k0 + r + i) * N + n0 + c];
  __syncthreads();
#pragma unroll
  for (int i = 0; i < 32; i += 8)
    dst[(size_t)(n0 + r + i) * 2048 + k0 + c] = f2bf(tile[c][r + i]);
}

// ---------------- GEMM QKV (dbuf, XCD swizzle) + bias + fused RoPE + fused V-transpose ----------
__global__ __launch_bounds__(256, 2) void gemm_qkv_k(
    const ushort_t* __restrict__ A, const ushort_t* __restrict__ Bt, ushort_t* __restrict__ C,
    const float* __restrict__ bq, const float* __restrict__ bk2, const float* __restrict__ bv,
    const float* __restrict__ cosT, const float* __restrict__ sinT, ushort_t* __restrict__ vt) {
  const int N = 3072, K = 2048;
  __shared__ ushort_t smem[16384];   // 32 KB: staging dbuf; later transpose tile / rope fbuf
  ushort_t* lA0 = smem;              // [2][4096], source-pre-swizzled: slot ^= (row>>1)&3
  ushort_t* lB0 = smem + 8192;
  const int lin = blockIdx.x;                    // 768 blocks
  const int nid = (lin & 7) * 96 + (lin >> 3);   // XCD-chunked swizzle (768%8==0)
  const int n0 = (nid % 24) * 128, m0 = (nid / 24) * 128;
  const int t = threadIdx.x;
  const int w = t >> 6, l = t & 63, lr = l & 15, lg = l >> 4;
  const int wr = w >> 1, wc = w & 1;
  const int srow = t >> 2, ssl = t & 3;

  auto stage = [&](int kt, int bufi) {
    int r0 = srow, r1 = srow + 64;
    gl_lds16(A + (size_t)(m0 + r0) * K + kt + ((ssl ^ ((r0 >> 1) & 3)) << 3),
             &lA0[bufi * 4096 + w * 512]);
    gl_lds16(A + (size_t)(m0 + r1) * K + kt + ((ssl ^ ((r1 >> 1) & 3)) << 3),
             &lA0[bufi * 4096 + 2048 + w * 512]);
    gl_lds16(Bt + (size_t)(n0 + r0) * K + kt + ((ssl ^ ((r0 >> 1) & 3)) << 3),
             &lB0[bufi * 4096 + w * 512]);
    gl_lds16(Bt + (size_t)(n0 + r1) * K + kt + ((ssl ^ ((r1 >> 1) & 3)) << 3),
             &lB0[bufi * 4096 + 2048 + w * 512]);
  };

  f32x4 acc[4][4];
#pragma unroll
  for (int i = 0; i < 4; i++)
#pragma unroll
    for (int j = 0; j < 4; j++) acc[i][j] = (f32x4){0.f, 0.f, 0.f, 0.f};

  stage(0, 0);
  const int nit = K / 32;   // 64
  for (int it = 0; it < nit; it++) {
    const int cur = it & 1;
    if (it + 1 < nit) {
      stage((it + 1) * 32, cur ^ 1);
      asm volatile("s_waitcnt vmcnt(4)" ::: "memory");   // current tile's 4 loads done
    } else {
      asm volatile("s_waitcnt vmcnt(0)" ::: "memory");
    }
    __builtin_amdgcn_s_barrier();
    short8 af[4], bfr[4];
#pragma unroll
    for (int mi = 0; mi < 4; mi++) {
      int row = wr * 64 + mi * 16 + lr;
      af[mi] = *(const short8*)((const char*)(lA0 + cur * 4096) + row * 64 +
                                ((lg ^ ((row >> 1) & 3)) << 4));
    }
#pragma unroll
    for (int ni = 0; ni < 4; ni++) {
      int row = wc * 64 + ni * 16 + lr;
      bfr[ni] = *(const short8*)((const char*)(lB0 + cur * 4096) + row * 64 +
                                 ((lg ^ ((row >> 1) & 3)) << 4));
    }
#pragma unroll
    for (int mi = 0; mi < 4; mi++)
#pragma unroll
      for (int ni = 0; ni < 4; ni++)
        acc[mi][ni] = __builtin_amdgcn_mfma_f32_16x16x32_bf16(af[mi], bfr[ni], acc[mi][ni], 0, 0, 0);
    __builtin_amdgcn_s_barrier();   // all waves done reading buf[cur] before restage
  }

  // epilogue: bias; RoPE (Q/K blocks) via partner-wave LDS exchange; V blocks also fill
  // the LDS transpose tile for the fused vt write.
  const bool isV = (n0 >= 2560);
  float* fbuf = (float*)smem;        // 16 KB, staging done
  const int pw_ = w ^ 1;             // partner wave: same wr, wc^1
#pragma unroll
  for (int mi = 0; mi < 4; mi++) {
    float vv[4][4];
#pragma unroll
    for (int ni = 0; ni < 4; ni++)
#pragma unroll
      for (int r = 0; r < 4; r++) {
        int col = n0 + wc * 64 + ni * 16 + lr;
        float bias = (col < 2048) ? bq[col] : (col < 2560) ? bk2[col - 2048] : bv[col - 2560];
        vv[ni][r] = acc[mi][ni][r] + bias;
      }
    if (!isV) {
      __syncthreads();
#pragma unroll
      for (int ni = 0; ni < 4; ni++)
#pragma unroll
        for (int r = 0; r < 4; r++)
          fbuf[w * 1024 + (lg * 4 + r) * 64 + ni * 16 + lr] = vv[ni][r];
      __syncthreads();
#pragma unroll
      for (int ni = 0; ni < 4; ni++)
#pragma unroll
        for (int r = 0; r < 4; r++) {
          float pv = fbuf[pw_ * 1024 + (lg * 4 + r) * 64 + ni * 16 + lr];
          int row = m0 + wr * 64 + mi * 16 + lg * 4 + r;   // = b*2048+s
          int d = wc * 64 + ni * 16 + lr;                  // 0..127 within head
          float c = cosT[(size_t)row * HD_ + d];
          float sn = sinT[(size_t)row * HD_ + d];
          vv[ni][r] = (wc == 0) ? vv[ni][r] * c - pv * sn : vv[ni][r] * c + pv * sn;
        }
    }
#pragma unroll
    for (int ni = 0; ni < 4; ni++)
#pragma unroll
      for (int r = 0; r < 4; r++) {
        int row = m0 + wr * 64 + mi * 16 + lg * 4 + r;
        int col = n0 + wc * 64 + ni * 16 + lr;
        ushort_t hv = f2bf(vv[ni][r]);
        C[(size_t)row * N + col] = hv;
        if (isV) {
          int colL = wc * 64 + ni * 16 + lr;            // d within head
          int rowL = wr * 64 + mi * 16 + lg * 4 + r;    // s within tile
          smem[colL * 128 + (rowL ^ ((colL & 7) << 4))] = hv;
        }
      }
  }
  if (isV) {
    __syncthreads();
    const int kvh = (n0 - 2560) >> 7;
    const int b = m0 >> 11, s0v = m0 & 2047;
    const size_t vbase = (size_t)(b * 4 + kvh) * 128;
#pragma unroll
    for (int j = 0; j < 8; j++) {
      int cid = j * 256 + t;
      int d = cid >> 4, sc = cid & 15;
      int rowStart = (sc * 8) ^ ((d & 7) << 4);
      short8 v8 = *(const short8*)&smem[d * 128 + rowStart];
      *(short8*)&vt[(vbase + d) * S_ + s0v + sc * 8] = v8;
    }
  }
}

// ---------------- fused causal GQA attention + attn_weights, single pass + norm sweep ---------
// 512 blocks (XCD-chunk swizzled; each XCD chunk shares one (b,kvh) K/V panel -> L2-hot).
// Block handles q-tiles {pi, 31-pi}: constant 33 k-tiles. Per q-tile:
//  sweep 1: QK^T + exp2 + PV accumulate (dbuf K+V), row-sum -> inv_l in registers
//  epilogue: normalized attnO (bf16) + zero-fill of outW upper triangle
//  sweep 2: QK^T recompute (dbuf K only, L2-hot) -> outW = exp2 * inv_l (fp32, causal region)
__global__ __launch_bounds__(256, 2) void attn_k(
    const ushort_t* __restrict__ qkv, const ushort_t* __restrict__ vt,
    ushort_t* __restrict__ attnO, float* __restrict__ outW) {
  __shared__ ushort_t lK[2][64 * 128];   // [k][d], 16 slots/row, slot ^= row&15
  __shared__ ushort_t lV[2][128 * 64];   // [d][k], 8 slots/row,  slot ^= row&7
  __shared__ ushort_t lP[4][16 * 64];    // per-wave P~ (16 rows), slot ^= row&7
  const int nid = (blockIdx.x & 7) * 64 + (blockIdx.x >> 3);   // 512%8==0, bijective
  const int pairI = nid & 15, h = (nid >> 4) & 15, b = nid >> 8;
  const int kvh = h >> 2;
  const int t = threadIdx.x, w = t >> 6, l = t & 63, lr = l & 15, lg = l >> 4;
  ushort_t* lPw = lP[w];

  auto stageKV = [&](int kt, int bufi) {
#pragma unroll
    for (int c = 0; c < 4; c++) {
      int row = c * 16 + (t >> 4), sl = t & 15;
      gl_lds16(qkv + (size_t)(b * S_ + kt * 64 + row) * 3072 + 2048 + kvh * HD_ +
                   ((sl ^ (row & 15)) << 3),
               &lK[bufi][c * 2048 + w * 512]);
    }
#pragma unroll
    for (int c = 0; c < 4; c++) {
      int row = c * 32 + (t >> 3), sl = t & 7;
      gl_lds16(vt + (size_t)((b * 4 + kvh) * 128 + row) * S_ + kt * 64 +
                   ((sl ^ (row & 7)) << 3),
               &lV[bufi][c * 2048 + w * 512]);
    }
  };
  auto stageK = [&](int kt, int bufi) {
#pragma unroll
    for (int c = 0; c < 4; c++) {
      int row = c * 16 + (t >> 4), sl = t & 15;
      gl_lds16(qkv + (size_t)(b * S_ + kt * 64 + row) * 3072 + 2048 + kvh * HD_ +
                   ((sl ^ (row & 15)) << 3),
               &lK[bufi][c * 2048 + w * 512]);
    }
  };

  for (int sel = 0; sel < 2; sel++) {
    const int qt = sel ? (31 - pairI) : pairI;   // 64-row q-tile index, 0..31
    const int qw = qt * 64 + w * 16;             // this wave's 16 q-rows
    const int nkt = qt + 1;                      // 64-wide k-tiles in causal range

    // Q fragments (A-frag: row=lane&15, k=(lane>>4)*8+i)
    short8 qf[4];
#pragma unroll
    for (int kc = 0; kc < 4; kc++)
      qf[kc] = *(const short8*)&qkv[(size_t)(b * S_ + qw + lr) * 3072 + h * HD_ + kc * 32 + lg * 8];

    float lsum[4];
    f32x4 o[8];
#pragma unroll
    for (int r = 0; r < 4; r++) lsum[r] = 0.f;
#pragma unroll
    for (int dj = 0; dj < 8; dj++) o[dj] = (f32x4){0.f, 0.f, 0.f, 0.f};

    // ======== sweep 1: attention accumulate ========
    stageKV(0, 0);
    for (int kt = 0; kt < nkt; kt++) {
      const int cur = kt & 1;
      if (kt + 1 < nkt) {
        stageKV(kt + 1, cur ^ 1);
        asm volatile("s_waitcnt vmcnt(8)" ::: "memory");   // current tile's 8 loads done
      } else {
        asm volatile("s_waitcnt vmcnt(0)" ::: "memory");
      }
      __builtin_amdgcn_s_barrier();

      // S = Q K^T
      f32x4 s[4];
#pragma unroll
      for (int ni = 0; ni < 4; ni++) s[ni] = (f32x4){0.f, 0.f, 0.f, 0.f};
      __builtin_amdgcn_s_setprio(1);
#pragma unroll
      for (int kc = 0; kc < 4; kc++) {
        short8 kf[4];
#pragma unroll
        for (int ni = 0; ni < 4; ni++) {
          int row = ni * 16 + lr;
          kf[ni] = *(const short8*)((const char*)lK[cur] + row * 256 +
                                    (((kc * 4 + lg) ^ (row & 15)) << 4));
        }
#pragma unroll
        for (int ni = 0; ni < 4; ni++)
          s[ni] = __builtin_amdgcn_mfma_f32_16x16x32_bf16(qf[kc], kf[ni], s[ni], 0, 0, 0);
      }
      __builtin_amdgcn_s_setprio(0);

      // P~ = exp2(S*C2); mask only on the diagonal tile (separate clean path otherwise)
      if (kt == nkt - 1) {
#pragma unroll
        for (int ni = 0; ni < 4; ni++)
#pragma unroll
          for (int r = 0; r < 4; r++) {
            float p = exp2f(s[ni][r] * C2_);
            int colg = kt * 64 + ni * 16 + lr;
            int rowg = qw + lg * 4 + r;
            if (colg > rowg) p = 0.f;
            lsum[r] += p;
            int rowl = lg * 4 + r, col = ni * 16 + lr;
            lPw[rowl * 64 + (((col >> 3) ^ (rowl & 7)) << 3) + (col & 7)] = f2bf2(p);
          }
      } else {
#pragma unroll
        for (int ni = 0; ni < 4; ni++)
#pragma unroll
          for (int r = 0; r < 4; r++) {
            float p = exp2f(s[ni][r] * C2_);
            lsum[r] += p;
            int rowl = lg * 4 + r, col = ni * 16 + lr;
            lPw[rowl * 64 + (((col >> 3) ^ (rowl & 7)) << 3) + (col & 7)] = f2bf2(p);
          }
      }

      // O += P~ V
      __builtin_amdgcn_s_setprio(1);
#pragma unroll
      for (int kc = 0; kc < 2; kc++) {
        short8 pa;
        {
          int row = lr;
          pa = *(const short8*)((const char*)lPw + row * 128 + (((kc * 4 + lg) ^ (row & 7)) << 4));
        }
#pragma unroll
        for (int dj = 0; dj < 8; dj++) {
          int row = dj * 16 + lr;
          short8 vb = *(const short8*)((const char*)lV[cur] + row * 128 +
                                       (((kc * 4 + lg) ^ (row & 7)) << 4));
          o[dj] = __builtin_amdgcn_mfma_f32_16x16x32_bf16(pa, vb, o[dj], 0, 0, 0);
        }
      }
      __builtin_amdgcn_s_setprio(0);
      __builtin_amdgcn_s_barrier();   // all waves done reading buf[cur] before restage
    }

    // row-sum reduce over the 16 lr lanes -> inv_l (registers only)
    float inv_l[4];
#pragma unroll
    for (int r = 0; r < 4; r++) {
      float sum = lsum[r];
#pragma unroll
      for (int off = 1; off < 16; off <<= 1) sum += __shfl_xor(sum, off);
      inv_l[r] = 1.f / sum;
    }
    // normalized O -> attn buffer (bf16)
#pragma unroll
    for (int dj = 0; dj < 8; dj++)
#pragma unroll
      for (int r = 0; r < 4; r++) {
        int rowg = b * S_ + qw + lg * 4 + r;
        int colg = h * HD_ + dj * 16 + lr;
        attnO[(size_t)rowg * Dm + colg] = f2bf(o[dj][r] * inv_l[r]);
      }

    // zero-fill outW strict upper triangle for this wave's 16 rows (cols >= nkt*64).
    {
      const int zc0 = nkt * 64;
      const int zn = (S_ - zc0) >> 2;   // float4 per row (multiple of 16, may be 0)
      f32x4 z = {0.f, 0.f, 0.f, 0.f};
      const int bh = b * NH + h;
      for (int rr = 0; rr < 16; rr++) {
        f32x4* base = (f32x4*)&outW[((size_t)bh * S_ + qw + rr) * S_ + zc0];
        for (int cc = l; cc < zn; cc += 64) __builtin_nontemporal_store(z, base + cc);
      }
    }

    // ======== sweep 2: recompute QK^T (K only, L2-hot), write normalized fp32 outW ========
    {
      const int bh = b * NH + h;
      stageK(0, 0);
      for (int kt = 0; kt < nkt; kt++) {
        const int cur = kt & 1;
        if (kt + 1 < nkt) {
          stageK(kt + 1, cur ^ 1);
          asm volatile("s_waitcnt vmcnt(4)" ::: "memory");
        } else {
          asm volatile("s_waitcnt vmcnt(0)" ::: "memory");
        }
        __builtin_amdgcn_s_barrier();

        f32x4 s[4];
#pragma unroll
        for (int ni = 0; ni < 4; ni++) s[ni] = (f32x4){0.f, 0.f, 0.f, 0.f};
        __builtin_amdgcn_s_setprio(1);
#pragma unroll
        for (int kc = 0; kc < 4; kc++) {
          short8 kf[4];
#pragma unroll
          for (int ni = 0; ni < 4; ni++) {
            int row = ni * 16 + lr;
            kf[ni] = *(const short8*)((const char*)lK[cur] + row * 256 +
                                      (((kc * 4 + lg) ^ (row & 15)) << 4));
          }
#pragma unroll
          for (int ni = 0; ni < 4; ni++)
            s[ni] = __builtin_amdgcn_mfma_f32_16x16x32_bf16(qf[kc], kf[ni], s[ni], 0, 0, 0);
        }
        __builtin_amdgcn_s_setprio(0);

        const bool diag = (kt == nkt - 1);
#pragma unroll
        for (int ni = 0; ni < 4; ni++)
#pragma unroll
          for (int r = 0; r < 4; r++) {
            int colg = kt * 64 + ni * 16 + lr;
            int rowg = qw + lg * 4 + r;
            float p = exp2f(s[ni][r] * C2_) * inv_l[r];
            if (diag && colg > rowg) p = 0.f;
            outW[((size_t)bh * S_ + rowg) * S_ + colg] = p;
          }
        __builtin_amdgcn_s_barrier();   // all waves done reading lK[cur] before restage
      }
    }
  }
}

// ---------------- tail: pure Wo projection GEMM (dbuf, XCD swizzle), full machine -------------
__global__ __launch_bounds__(256, 2) void tail_k(
    const ushort_t* __restrict__ A, const ushort_t* __restrict__ Bt, float* __restrict__ outO) {
  __shared__ ushort_t sh[2][64 * 128];   // 32 KB
  const int t = threadIdx.x;
  const int w = t >> 6, l = t & 63, lr = l & 15, lg = l >> 4;
  const int N = 2048, K = 2048;
  const int nid = (blockIdx.x & 7) * 64 + (blockIdx.x >> 3);   // XCD-chunked, 512%8==0
  const int n0 = (nid & 15) * 128, m0 = (nid >> 4) * 128;
  const int wr = w >> 1, wc = w & 1;
  const int srow = t >> 2, ssl = t & 3;

  auto stageG = [&](int kt, int bufi) {
    int r0 = srow, r1 = srow + 64;
    gl_lds16(A + (size_t)(m0 + r0) * K + kt + ((ssl ^ ((r0 >> 1) & 3)) << 3), &sh[bufi][w * 512]);
    gl_lds16(A + (size_t)(m0 + r1) * K + kt + ((ssl ^ ((r1 >> 1) & 3)) << 3),
             &sh[bufi][2048 + w * 512]);
    gl_lds16(Bt + (size_t)(n0 + r0) * K + kt + ((ssl ^ ((r0 >> 1) & 3)) << 3),
             &sh[bufi][4096 + w * 512]);
    gl_lds16(Bt + (size_t)(n0 + r1) * K + kt + ((ssl ^ ((r1 >> 1) & 3)) << 3),
             &sh[bufi][4096 + 2048 + w * 512]);
  };

  f32x4 acc[4][4];
#pragma unroll
  for (int i = 0; i < 4; i++)
#pragma unroll
    for (int j = 0; j < 4; j++) acc[i][j] = (f32x4){0.f, 0.f, 0.f, 0.f};

  stageG(0, 0);
  const int nit = K / 32;
  for (int it = 0; it < nit; it++) {
    const int cur = it & 1;
    if (it + 1 < nit) {
      stageG((it + 1) * 32, cur ^ 1);
      asm volatile("s_waitcnt vmcnt(4)" ::: "memory");
    } else {
      asm volatile("s_waitcnt vmcnt(0)" ::: "memory");
    }
    __builtin_amdgcn_s_barrier();
    short8 af[4], bfr[4];
#pragma unroll
    for (int mi = 0; mi < 4; mi++) {
      int row = wr * 64 + mi * 16 + lr;
      af[mi] =
          *(const short8*)((const char*)&sh[cur][0] + row * 64 + ((lg ^ ((row >> 1) & 3)) << 4));
    }
#pragma unroll
    for (int ni = 0; ni < 4; ni++) {
      int row = wc * 64 + ni * 16 + lr;
      bfr[ni] = *(const short8*)((const char*)&sh[cur][4096] + row * 64 +
                                 ((lg ^ ((row >> 1) & 3)) << 4));
    }
#pragma unroll
    for (int mi = 0; mi < 4; mi++)
#pragma unroll
      for (int ni = 0; ni < 4; ni++)
        acc[mi][ni] =
            __builtin_amdgcn_mfma_f32_16x16x32_bf16(af[mi], bfr[ni], acc[mi][ni], 0, 0, 0);
    __builtin_amdgcn_s_barrier();
  }
#pragma unroll
  for (int mi = 0; mi < 4; mi++)
#pragma unroll
    for (int ni = 0; ni < 4; ni++)
#pragma unroll
      for (int r = 0; r < 4; r++) {
        int row = m0 + wr * 64 + mi * 16 + lg * 4 + r;
        int col = n0 + wc * 64 + ni * 16 + lr;
        outO[(size_t)row * N + col] = acc[mi][ni][r];
      }
}

// ---------------- host ----------------
extern "C" void kernel_launch(void* const* d_in, const int* in_sizes, int n_in,
                              void* d_out, int out_size, void* d_ws, size_t ws_size,
                              hipStream_t stream) {
  const float* hs   = (const float*)d_in[0];
  const float* cosT = (const float*)d_in[1];
  const float* sinT = (const float*)d_in[2];
  // d_in[3] attention_mask: pure causal, applied analytically
  const float* Wq = (const float*)d_in[4];
  const float* bq = (const float*)d_in[5];
  const float* Wk = (const float*)d_in[6];
  const float* bk = (const float*)d_in[7];
  const float* Wv = (const float*)d_in[8];
  const float* bv = (const float*)d_in[9];
  const float* Wo = (const float*)d_in[10];

  char* ws = (char*)d_ws;
  ushort_t* hsb   = (ushort_t*)(ws);               // 16,777,216 B  [4096][2048] bf16
  ushort_t* wtqkv = (ushort_t*)(ws + 16777216);    // 12,582,912 B  [3072][2048] bf16 (Wq|Wk|Wv)^T
  ushort_t* wto   = (ushort_t*)(ws + 29360128);    //  8,388,608 B  [2048][2048] bf16 Wo^T
  ushort_t* qkv   = (ushort_t*)(ws + 37748736);    // 25,165,824 B  [4096][3072] bf16
  ushort_t* vt    = (ushort_t*)(ws + 62914560);    //  4,194,304 B  [8][128][2048] bf16
  ushort_t* attn  = (ushort_t*)(ws);               // reuse hsb region (dead after gemm_qkv)

  float* outO = (float*)d_out;            // [2,2048,2048] attn_out
  float* outW = outO + (size_t)8388608;   // [2,16,2048,2048] attn_weights

  prep_k<<<8192 + 16384, 256, 0, stream>>>(hs, hsb, Wq, Wk, Wv, Wo, wtqkv, wto);
  gemm_qkv_k<<<768, 256, 0, stream>>>(hsb, wtqkv, qkv, bq, bk, bv, cosT, sinT, vt);
  attn_k<<<512, 256, 0, stream>>>(qkv, vt, attn, outW);
  tail_k<<<512, 256, 0, stream>>>(attn, wto, outO);
}